// Round 1
// baseline (303.364 us; speedup 1.0000x reference)
//
#include <hip/hip_runtime.h>
#include <hip/hip_bf16.h>

// SimCLR NT-Xent loss. B=4096, D=256, N=2B=8192 rows.
// loss = (1/N) sum_i [ log(denom_i) - log(pos_i) ]
//   denom_i = sum_{j!=i} exp(sim_ij / T),  T=0.5  -> exp(2*sim)
//   pos_i   = sim[i, (i+B) mod N]  (raw cosine of the positive pair)

#define NROWS 8192
#define BHALF 4096
#define DDIM  256
#define JCHUNKS 8
#define JT_TOTAL (NROWS / 16)            // 512 j-tiles
#define JT_PER_CHUNK (JT_TOTAL / JCHUNKS) // 64

typedef __attribute__((ext_vector_type(8))) short bf16x8;
typedef __attribute__((ext_vector_type(4))) float f32x4;

__device__ __forceinline__ unsigned short f2bf(float f) {
    __hip_bfloat16 h = __float2bfloat16(f);
    return __builtin_bit_cast(unsigned short, h);
}

// Kernel 1: row norms + normalized bf16 matrix. One wave per row (4 rows/block).
__global__ __launch_bounds__(256) void prep_kernel(const float* __restrict__ z1,
                                                   const float* __restrict__ z2,
                                                   unsigned short* __restrict__ zn,
                                                   float* __restrict__ norms) {
    int row  = blockIdx.x * 4 + (threadIdx.x >> 6);
    int lane = threadIdx.x & 63;
    const float* src = (row < BHALF) ? (z1 + (size_t)row * DDIM)
                                     : (z2 + (size_t)(row - BHALF) * DDIM);
    float4 v = reinterpret_cast<const float4*>(src)[lane];
    float ss = v.x * v.x + v.y * v.y + v.z * v.z + v.w * v.w;
    #pragma unroll
    for (int off = 32; off; off >>= 1) ss += __shfl_xor(ss, off);
    float norm = fmaxf(sqrtf(ss), 1e-8f);
    if (lane == 0) norms[row] = norm;
    float inv = 1.0f / norm;
    ushort4 o;
    o.x = f2bf(v.x * inv);
    o.y = f2bf(v.y * inv);
    o.z = f2bf(v.z * inv);
    o.w = f2bf(v.w * inv);
    reinterpret_cast<ushort4*>(zn + (size_t)row * DDIM)[lane] = o;
}

// Kernel 2: positive-pair cosine in full fp32 from raw inputs. One wave per i.
__global__ __launch_bounds__(256) void pos_kernel(const float* __restrict__ z1,
                                                  const float* __restrict__ z2,
                                                  const float* __restrict__ norms,
                                                  float* __restrict__ pos) {
    int i    = blockIdx.x * 4 + (threadIdx.x >> 6);
    int lane = threadIdx.x & 63;
    float4 a = reinterpret_cast<const float4*>(z1 + (size_t)i * DDIM)[lane];
    float4 b = reinterpret_cast<const float4*>(z2 + (size_t)i * DDIM)[lane];
    float d = a.x * b.x + a.y * b.y + a.z * b.z + a.w * b.w;
    #pragma unroll
    for (int off = 32; off; off >>= 1) d += __shfl_xor(d, off);
    if (lane == 0) {
        float p = d / (norms[i] * norms[i + BHALF]);
        pos[i] = p;
        pos[i + BHALF] = p;
    }
}

// Kernel 3: fused sim-GEMM + exp row-sum.
// Block = 4 waves; wave w owns 16 rows (rowBase..+15), A-frags live in registers
// for the whole j sweep. Each block sweeps JT_PER_CHUNK j-tiles (all 4 waves on
// the same j -> B-frag loads hit L1). 2 j-tiles in flight for MFMA ILP.
__global__ __launch_bounds__(256) void denom_kernel(const unsigned short* __restrict__ zn,
                                                    float* __restrict__ denom) {
    int lane = threadIdx.x & 63;
    int wave = threadIdx.x >> 6;
    int col  = lane & 15;
    int quad = lane >> 4;
    int rowBase = blockIdx.x * 64 + wave * 16;     // blockIdx.x in [0,128)
    int jtBase  = blockIdx.y * JT_PER_CHUNK;       // blockIdx.y in [0,JCHUNKS)

    // A fragment: lane holds A[m=col][k = ks*32 + quad*8 + j], j=0..7 (16B contiguous)
    bf16x8 a[8];
    const unsigned short* arow = zn + (size_t)(rowBase + col) * DDIM + quad * 8;
    #pragma unroll
    for (int ks = 0; ks < 8; ks++)
        a[ks] = *reinterpret_cast<const bf16x8*>(arow + ks * 32);

    float rs[4] = {0.f, 0.f, 0.f, 0.f};

    for (int jj = 0; jj < JT_PER_CHUNK; jj += 2) {
        int j0 = (jtBase + jj) * 16;
        int j1 = j0 + 16;
        const unsigned short* b0p = zn + (size_t)(j0 + col) * DDIM + quad * 8;
        const unsigned short* b1p = zn + (size_t)(j1 + col) * DDIM + quad * 8;
        bf16x8 b0[8], b1[8];
        #pragma unroll
        for (int ks = 0; ks < 8; ks++) {
            b0[ks] = *reinterpret_cast<const bf16x8*>(b0p + ks * 32);
            b1[ks] = *reinterpret_cast<const bf16x8*>(b1p + ks * 32);
        }
        f32x4 acc0 = {0.f, 0.f, 0.f, 0.f};
        f32x4 acc1 = {0.f, 0.f, 0.f, 0.f};
        #pragma unroll
        for (int ks = 0; ks < 8; ks++) {
            acc0 = __builtin_amdgcn_mfma_f32_16x16x32_bf16(a[ks], b0[ks], acc0, 0, 0, 0);
            acc1 = __builtin_amdgcn_mfma_f32_16x16x32_bf16(a[ks], b1[ks], acc1, 0, 0, 0);
        }
        // C layout: element (row = quad*4 + r, col = lane&15)
        if (j0 != rowBase) {
            #pragma unroll
            for (int r = 0; r < 4; r++) rs[r] += __expf(2.0f * acc0[r]);
        } else {
            #pragma unroll
            for (int r = 0; r < 4; r++)
                if (quad * 4 + r != col) rs[r] += __expf(2.0f * acc0[r]);
        }
        if (j1 != rowBase) {
            #pragma unroll
            for (int r = 0; r < 4; r++) rs[r] += __expf(2.0f * acc1[r]);
        } else {
            #pragma unroll
            for (int r = 0; r < 4; r++)
                if (quad * 4 + r != col) rs[r] += __expf(2.0f * acc1[r]);
        }
    }

    // reduce the 16 column-lanes of each quad, then one atomic per row
    #pragma unroll
    for (int r = 0; r < 4; r++) {
        float v = rs[r];
        v += __shfl_xor(v, 1);
        v += __shfl_xor(v, 2);
        v += __shfl_xor(v, 4);
        v += __shfl_xor(v, 8);
        if (col == 0) atomicAdd(&denom[rowBase + quad * 4 + r], v);
    }
}

// Kernel 4: final scalar reduction.
__global__ __launch_bounds__(256) void loss_kernel(const float* __restrict__ pos,
                                                   const float* __restrict__ denom,
                                                   float* __restrict__ out) {
    __shared__ float sdata[4];
    float s = 0.f;
    for (int i = threadIdx.x; i < NROWS; i += 256)
        s += __logf(denom[i]) - __logf(pos[i]);
    #pragma unroll
    for (int off = 32; off; off >>= 1) s += __shfl_xor(s, off);
    if ((threadIdx.x & 63) == 0) sdata[threadIdx.x >> 6] = s;
    __syncthreads();
    if (threadIdx.x == 0)
        out[0] = (sdata[0] + sdata[1] + sdata[2] + sdata[3]) * (1.0f / NROWS);
}

extern "C" void kernel_launch(void* const* d_in, const int* in_sizes, int n_in,
                              void* d_out, int out_size, void* d_ws, size_t ws_size,
                              hipStream_t stream) {
    const float* z1 = (const float*)d_in[0];
    const float* z2 = (const float*)d_in[1];

    // ws layout: zn bf16 [8192*256] (4 MB) | norms f32[8192] | pos f32[8192] | denom f32[8192]
    unsigned short* zn = (unsigned short*)d_ws;
    float* norms = (float*)((char*)d_ws + (size_t)NROWS * DDIM * sizeof(unsigned short));
    float* pos   = norms + NROWS;
    float* denom = pos + NROWS;

    hipMemsetAsync(denom, 0, NROWS * sizeof(float), stream);
    prep_kernel<<<NROWS / 4, 256, 0, stream>>>(z1, z2, zn, norms);
    pos_kernel<<<BHALF / 4, 256, 0, stream>>>(z1, z2, norms, pos);
    denom_kernel<<<dim3(NROWS / 64, JCHUNKS), 256, 0, stream>>>(zn, denom);
    loss_kernel<<<1, 256, 0, stream>>>(pos, denom, (float*)d_out);
}

// Round 2
// 166.248 us; speedup vs baseline: 1.8248x; 1.8248x over previous
//
#include <hip/hip_runtime.h>
#include <hip/hip_bf16.h>

// SimCLR NT-Xent loss. B=4096, D=256, N=2B=8192 rows.
// loss = (1/N) sum_i [ log(denom_i) - log(pos_i) ]
//   denom_i = sum_{j!=i} exp(2*sim_ij),  pos_i = cos(z_i, z_{i+-B})
//
// denom path: sim = zn @ zn^T via m97-style MFMA GEMM (128x128 tile,
// global_load_lds width-16 staging, BK=32), fused exp row-sum epilogue.

#define NROWS 8192
#define BHALF 4096
#define DDIM  256
#define BK    32

typedef __attribute__((ext_vector_type(8))) short bf16x8;
typedef __attribute__((ext_vector_type(4))) float f32x4;

__device__ __forceinline__ unsigned short f2bf(float f) {
    __hip_bfloat16 h = __float2bfloat16(f);
    return __builtin_bit_cast(unsigned short, h);
}

__device__ __forceinline__ void load_lds16(const unsigned short* g, unsigned short* l) {
    __builtin_amdgcn_global_load_lds(
        (const __attribute__((address_space(1))) void*)g,
        (__attribute__((address_space(3))) void*)l, 16, 0, 0);
}

// Kernel 1: fused norms + bf16-normalized matrix + positive-pair cosine +
// denom zero-init. One wave per pair index i (handles z1_i AND z2_i).
__global__ __launch_bounds__(256) void prep_kernel(const float* __restrict__ z1,
                                                   const float* __restrict__ z2,
                                                   unsigned short* __restrict__ zn,
                                                   float* __restrict__ pos,
                                                   float* __restrict__ denom) {
    int i    = blockIdx.x * 4 + (threadIdx.x >> 6);
    int lane = threadIdx.x & 63;
    float4 a = reinterpret_cast<const float4*>(z1 + (size_t)i * DDIM)[lane];
    float4 b = reinterpret_cast<const float4*>(z2 + (size_t)i * DDIM)[lane];
    float ss1 = a.x * a.x + a.y * a.y + a.z * a.z + a.w * a.w;
    float ss2 = b.x * b.x + b.y * b.y + b.z * b.z + b.w * b.w;
    float dd  = a.x * b.x + a.y * b.y + a.z * b.z + a.w * b.w;
    #pragma unroll
    for (int off = 32; off; off >>= 1) {
        ss1 += __shfl_xor(ss1, off);
        ss2 += __shfl_xor(ss2, off);
        dd  += __shfl_xor(dd, off);
    }
    float n1 = fmaxf(sqrtf(ss1), 1e-8f);
    float n2 = fmaxf(sqrtf(ss2), 1e-8f);
    float i1 = 1.0f / n1, i2 = 1.0f / n2;
    ushort4 oa, ob;
    oa.x = f2bf(a.x * i1); oa.y = f2bf(a.y * i1); oa.z = f2bf(a.z * i1); oa.w = f2bf(a.w * i1);
    ob.x = f2bf(b.x * i2); ob.y = f2bf(b.y * i2); ob.z = f2bf(b.z * i2); ob.w = f2bf(b.w * i2);
    reinterpret_cast<ushort4*>(zn + (size_t)i * DDIM)[lane] = oa;
    reinterpret_cast<ushort4*>(zn + (size_t)(i + BHALF) * DDIM)[lane] = ob;
    if (lane == 0) pos[i] = dd * i1 * i2;
    if (threadIdx.x < 8) denom[blockIdx.x * 8 + threadIdx.x] = 0.0f;
}

// Kernel 2: MFMA sim-GEMM + exp row-sum (m97 structure).
// 128x128 C-tile/block, 4 waves in 2x2, each wave 64x64 = 4x4 of 16x16x32.
// LDS XOR swizzle keeps global_load_lds lane-contiguity AND 2-way-free
// fragment ds_read_b128 banking.
__global__ __launch_bounds__(256) void denom_kernel(const unsigned short* __restrict__ zn,
                                                    float* __restrict__ denom) {
    __shared__ __align__(16) unsigned short sA[128 * BK];
    __shared__ __align__(16) unsigned short sB[128 * BK];

    int t    = threadIdx.x;
    int lane = t & 63;
    int wave = t >> 6;
    int col  = lane & 15;
    int quad = lane >> 4;
    int wm = wave >> 1, wn = wave & 1;
    int rowA0 = blockIdx.y * 128;   // i-rows of this block
    int rowB0 = blockIdx.x * 128;   // j-cols of this block

    // staging: 2 lds-load instrs per tile; slot s (16B) holds row r=s/4,
    // chunk c = (s&3) ^ ((r>>1)&3) of the current 32-elem k-window.
    int r0 = t >> 2, c0 = (t & 3) ^ ((r0 >> 1) & 3);
    int s1 = 256 + t;
    int r1 = s1 >> 2, c1 = (s1 & 3) ^ ((r1 >> 1) & 3);
    const unsigned short* gA0 = zn + (size_t)(rowA0 + r0) * DDIM + c0 * 8;
    const unsigned short* gA1 = zn + (size_t)(rowA0 + r1) * DDIM + c1 * 8;
    const unsigned short* gB0 = zn + (size_t)(rowB0 + r0) * DDIM + c0 * 8;
    const unsigned short* gB1 = zn + (size_t)(rowB0 + r1) * DDIM + c1 * 8;
    unsigned short* lA0 = sA + (size_t)t * 8;
    unsigned short* lA1 = sA + (size_t)s1 * 8;
    unsigned short* lB0 = sB + (size_t)t * 8;
    unsigned short* lB1 = sB + (size_t)s1 * 8;

    // fragment read pointers: row rA = wm*64 + mt*16 + col, chunk q=quad,
    // slot = rA*4 + (quad ^ sig), sig = (col>>1)&3 (mt-invariant).
    int sig = (col >> 1) & 3;
    const bf16x8* pa = (const bf16x8*)(sA + ((size_t)((wm * 64 + col) * 4 + (quad ^ sig))) * 8);
    const bf16x8* pb = (const bf16x8*)(sB + ((size_t)((wn * 64 + col) * 4 + (quad ^ sig))) * 8);

    f32x4 acc[4][4];
    #pragma unroll
    for (int mt = 0; mt < 4; mt++)
        #pragma unroll
        for (int nt = 0; nt < 4; nt++)
            acc[mt][nt] = (f32x4){0.f, 0.f, 0.f, 0.f};

    for (int kt = 0; kt < 8; kt++) {
        int ko = kt * BK;
        load_lds16(gA0 + ko, lA0);
        load_lds16(gA1 + ko, lA1);
        load_lds16(gB0 + ko, lB0);
        load_lds16(gB1 + ko, lB1);
        __syncthreads();
        bf16x8 af[4], bf[4];
        #pragma unroll
        for (int mt = 0; mt < 4; mt++) af[mt] = pa[mt * 64];
        #pragma unroll
        for (int nt = 0; nt < 4; nt++) bf[nt] = pb[nt * 64];
        #pragma unroll
        for (int mt = 0; mt < 4; mt++)
            #pragma unroll
            for (int nt = 0; nt < 4; nt++)
                acc[mt][nt] = __builtin_amdgcn_mfma_f32_16x16x32_bf16(af[mt], bf[nt], acc[mt][nt], 0, 0, 0);
        __syncthreads();
    }

    // epilogue: exp(2*sim), mask self-diagonal, row-sum.
    // C layout: row = quad*4 + rr (A-row), col = lane&15 (B-row).
    int rBase = rowA0 + wm * 64;
    int cBase = rowB0 + wn * 64;
    float rs[4][4];
    #pragma unroll
    for (int mt = 0; mt < 4; mt++)
        #pragma unroll
        for (int rr = 0; rr < 4; rr++) rs[mt][rr] = 0.f;

    #pragma unroll
    for (int mt = 0; mt < 4; mt++) {
        #pragma unroll
        for (int nt = 0; nt < 4; nt++) {
            bool diagTile = (rBase + mt * 16) == (cBase + nt * 16);
            f32x4 v = acc[mt][nt];
            #pragma unroll
            for (int rr = 0; rr < 4; rr++) {
                float e = __expf(2.0f * v[rr]);
                if (diagTile && (quad * 4 + rr) == col) e = 0.f;
                rs[mt][rr] += e;
            }
        }
    }
    #pragma unroll
    for (int mt = 0; mt < 4; mt++) {
        #pragma unroll
        for (int rr = 0; rr < 4; rr++) {
            float x = rs[mt][rr];
            x += __shfl_xor(x, 1);
            x += __shfl_xor(x, 2);
            x += __shfl_xor(x, 4);
            x += __shfl_xor(x, 8);
            if (col == 0)
                atomicAdd(&denom[rBase + mt * 16 + quad * 4 + rr], x);
        }
    }
}

// Kernel 3: final scalar reduction. pos has BHALF entries, each counted twice.
__global__ __launch_bounds__(256) void loss_kernel(const float* __restrict__ pos,
                                                   const float* __restrict__ denom,
                                                   float* __restrict__ out) {
    __shared__ float sdata[4];
    float s = 0.f;
    for (int i = threadIdx.x; i < NROWS; i += 256)
        s += __logf(denom[i]);
    for (int i = threadIdx.x; i < BHALF; i += 256)
        s -= 2.0f * __logf(pos[i]);
    #pragma unroll
    for (int off = 32; off; off >>= 1) s += __shfl_xor(s, off);
    if ((threadIdx.x & 63) == 0) sdata[threadIdx.x >> 6] = s;
    __syncthreads();
    if (threadIdx.x == 0)
        out[0] = (sdata[0] + sdata[1] + sdata[2] + sdata[3]) * (1.0f / NROWS);
}

extern "C" void kernel_launch(void* const* d_in, const int* in_sizes, int n_in,
                              void* d_out, int out_size, void* d_ws, size_t ws_size,
                              hipStream_t stream) {
    const float* z1 = (const float*)d_in[0];
    const float* z2 = (const float*)d_in[1];

    // ws: zn bf16 [8192*256] (4 MB) | pos f32[4096] | denom f32[8192]
    unsigned short* zn = (unsigned short*)d_ws;
    float* pos   = (float*)((char*)d_ws + (size_t)NROWS * DDIM * sizeof(unsigned short));
    float* denom = pos + BHALF;

    prep_kernel<<<BHALF / 4, 256, 0, stream>>>(z1, z2, zn, pos, denom);
    denom_kernel<<<dim3(NROWS / 128, NROWS / 128), 256, 0, stream>>>(zn, denom);
    loss_kernel<<<1, 256, 0, stream>>>(pos, denom, (float*)d_out);
}